// Round 12
// baseline (225.527 us; speedup 1.0000x reference)
//
#include <hip/hip_runtime.h>
#include <math.h>

#define NN 8192
#define DD 64
#define EE 64
#define NB 2
#define THRESH 0.7f
#define IC 64
#define LOG2E 1.4426950408889634f

typedef __attribute__((ext_vector_type(8))) short bf16x8;
typedef __attribute__((ext_vector_type(4))) float f32x4;
typedef __fp16 half2v __attribute__((ext_vector_type(2)));

static __device__ __forceinline__ short f2bf(float x) {  // RNE
    unsigned u = __float_as_uint(x);
    unsigned r = (u + 0x7fffu + ((u >> 16) & 1u)) >> 16;
    return (short)r;
}
static __device__ __forceinline__ unsigned pack_bf_trunc(float lo, float hi) {
    return __builtin_amdgcn_perm(__float_as_uint(hi), __float_as_uint(lo), 0x07060302u);
}
static __device__ __forceinline__ unsigned pk_f16(float a, float b) {
    half2v h = __builtin_amdgcn_cvt_pkrtz(a, b);
    return __builtin_bit_cast(unsigned, h);
}
static __device__ __forceinline__ float f16lo(unsigned u) {
    half2v h = __builtin_bit_cast(half2v, u);
    return (float)h[0];
}
static __device__ __forceinline__ float f16hi(unsigned u) {
    half2v h = __builtin_bit_cast(half2v, u);
    return (float)h[1];
}

// ---------------------------------------------------------------------------
// p_kernel: P = U@W -> bf16, U -> bf16. 2048 blocks x 256 (4 rows/block).
// ---------------------------------------------------------------------------
__global__ __launch_bounds__(256) void p_kernel(const float* __restrict__ U,
                                                const float* __restrict__ W,
                                                short* __restrict__ P_bf,
                                                short* __restrict__ U_bf) {
    __shared__ float Wl[4096];
    __shared__ float Ul[256];
    const int t = threadIdx.x;
#pragma unroll
    for (int k = 0; k < 4; ++k)
        ((float4*)Wl)[k * 256 + t] = ((const float4*)W)[k * 256 + t];
    const int r0 = blockIdx.x * 4;
    Ul[t] = U[r0 * EE + t];
    __syncthreads();
    const int row = t >> 6;
    const int f = t & 63;
    const float* ur = Ul + row * EE;
    float acc = 0.f;
#pragma unroll
    for (int e = 0; e < EE; ++e) acc = fmaf(ur[e], Wl[e * 64 + f], acc);
    P_bf[(r0 + row) * EE + f] = f2bf(acc);
    U_bf[(r0 + row) * EE + f] = f2bf(ur[f]);
}

// ---------------------------------------------------------------------------
// es_kernel: es_t[b*64+d][i] = bf16(relu(prof-thr)*state). 512 blocks x 256.
// ---------------------------------------------------------------------------
__global__ __launch_bounds__(256) void es_kernel(const float* __restrict__ S,
                                                 const float* __restrict__ prof,
                                                 short* __restrict__ es_t) {
    __shared__ float tr[64 * 33];
    __shared__ float gl[32];
    const int t = threadIdx.x;
    const int b = blockIdx.x >> 8;
    const int i0 = (blockIdx.x & 255) * 32;
    if (t < 32) gl[t] = fmaxf(prof[b * NN + i0 + t] - THRESH, 0.f);
#pragma unroll
    for (int k = 0; k < 2; ++k) {
        const int idx = k * 256 + t;
        const int i = idx >> 4, c4 = idx & 15;
        const float4 s = ((const float4*)S)[(b * NN + i0 + i) * 16 + c4];
        tr[(c4 * 4 + 0) * 33 + i] = s.x;
        tr[(c4 * 4 + 1) * 33 + i] = s.y;
        tr[(c4 * 4 + 2) * 33 + i] = s.z;
        tr[(c4 * 4 + 3) * 33 + i] = s.w;
    }
    __syncthreads();
    const int d = t >> 2;
    const int sg = (t & 3) * 8;
    bf16x8 v;
#pragma unroll
    for (int e = 0; e < 8; ++e) v[e] = f2bf(tr[d * 33 + sg + e] * gl[sg + e]);
    *(bf16x8*)(es_t + (size_t)(b * 64 + d) * NN + i0 + sg) = v;
}

// ---------------------------------------------------------------------------
// Transfer: round-6 body (proven), 256 threads (4 waves), IC=64.
// grid (128, nY). __launch_bounds__(256,8): VGPR cap 64 -> 8 blocks/CU
// by resources; grid 2048 makes 8/CU actually available. LDS 8 KB.
// ---------------------------------------------------------------------------
__global__ __launch_bounds__(256, 8) void transfer_kernel(const short* __restrict__ P_bf,
                                                          const short* __restrict__ U_bf,
                                                          const short* __restrict__ es_t,
                                                          const float* __restrict__ bias_p,
                                                          unsigned short* __restrict__ part) {
    // T in MFMA-A fragment order: [jt*2+ks][lane][8 shorts] = 8 KB
    __shared__ __align__(16) short TT[8 * 64 * 8];

    const int t = threadIdx.x;
    const int w = t >> 6;      // 0..3
    const int lane = t & 63;
    const int q = lane >> 4;
    const int ln = lane & 15;
    const int j0 = blockIdx.x * 64;
    const int span = NN / gridDim.y;
    const int i_base = blockIdx.y * span;
    const int nchunk = span / IC;
    const float nb = -bias_p[0] * LOG2E;

    // U B-fragments resident for the whole kernel
    bf16x8 uf[4][2];
#pragma unroll
    for (int jt = 0; jt < 4; ++jt)
#pragma unroll
        for (int ks = 0; ks < 2; ++ks)
            uf[jt][ks] = *(const bf16x8*)(U_bf + (j0 + jt * 16 + ln) * EE + ks * 32 + q * 8);

    f32x4 acc[4][2];
#pragma unroll
    for (int jm = 0; jm < 4; ++jm)
#pragma unroll
        for (int c = 0; c < 2; ++c) acc[jm][c] = (f32x4){0.f, 0.f, 0.f, 0.f};
    const f32x4 zero = (f32x4){0.f, 0.f, 0.f, 0.f};

    // producer TT slot: i_local = 16w+4q+r -> ks=(w>>1), qp=(2w+(q>>1))&3, half=q&1
    const int ks_w = w >> 1;
    const int qp = (2 * w + (q >> 1)) & 3;
    const int ttw_off = (ks_w * 64 + qp * 16 + ln) * 2 + (q & 1);  // uint2 units

    for (int chunk = 0; chunk < nchunk; ++chunk) {
        const int i0 = i_base + chunk * IC;
        const bool diag = (i0 == j0);

        // issue global fragment loads early (L2-resident)
        bf16x8 pf[2];
#pragma unroll
        for (int ks = 0; ks < 2; ++ks)
            pf[ks] = *(const bf16x8*)(P_bf + (i0 + w * 16 + ln) * EE + ks * 32 + q * 8);
        bf16x8 bfr[2][2];
#pragma unroll
        for (int c = 0; c < 2; ++c) {
            const int g = w * 2 + c;
            const short* er = es_t + (size_t)((g >> 2) * 64 + (g & 3) * 16 + ln) * NN + i0;
#pragma unroll
            for (int ks = 0; ks < 2; ++ks)
                bfr[c][ks] = *(const bf16x8*)(er + ks * 32 + q * 8);
        }

        __syncthreads();  // TT from previous chunk fully consumed

        // ---- phase A: scores -> sigmoid -> T in A-fragment order ----
#pragma unroll
        for (int jt = 0; jt < 4; ++jt) {
            f32x4 s = __builtin_amdgcn_mfma_f32_16x16x32_bf16(pf[0], uf[jt][0], zero, 0, 0, 0);
            s = __builtin_amdgcn_mfma_f32_16x16x32_bf16(pf[1], uf[jt][1], s, 0, 0, 0);
            float T[4];
#pragma unroll
            for (int r = 0; r < 4; ++r)
                T[r] = __builtin_amdgcn_rcpf(
                    1.f + __builtin_amdgcn_exp2f(fmaf(s[r], -LOG2E, nb)));
            if (diag && jt == w) {  // diagonal 64-chunk, wave-row == j-tile
                const int rr = ln - 4 * q;
                if (rr >= 0 && rr < 4) T[rr] = 0.f;
            }
            uint2 pk;
            pk.x = pack_bf_trunc(T[0], T[1]);
            pk.y = pack_bf_trunc(T[2], T[3]);
            ((uint2*)TT)[jt * 256 + ttw_off] = pk;
        }
        __syncthreads();  // TT complete

        // ---- phase B: acc[jm][c] += T^T * es ----
#pragma unroll
        for (int jm = 0; jm < 4; ++jm) {
#pragma unroll
            for (int ks = 0; ks < 2; ++ks) {
                const bf16x8 af = *(const bf16x8*)(TT + ((jm * 2 + ks) * 64 + lane) * 8);
                acc[jm][0] = __builtin_amdgcn_mfma_f32_16x16x32_bf16(af, bfr[0][ks], acc[jm][0], 0, 0, 0);
                acc[jm][1] = __builtin_amdgcn_mfma_f32_16x16x32_bf16(af, bfr[1][ks], acc[jm][1], 0, 0, 0);
            }
        }
    }

    // epilogue: fp16 partials, 64B/thread slab, fully coalesced
    unsigned short* pb = part + (size_t)(blockIdx.y * 128 + blockIdx.x) * 8192;
#pragma unroll
    for (int jm = 0; jm < 4; ++jm) {
        uint4 v;
        v.x = pk_f16(acc[jm][0][0], acc[jm][0][1]);
        v.y = pk_f16(acc[jm][0][2], acc[jm][0][3]);
        v.z = pk_f16(acc[jm][1][0], acc[jm][1][1]);
        v.w = pk_f16(acc[jm][1][2], acc[jm][1][3]);
        *(uint4*)(pb + jm * 2048 + t * 8) = v;
    }
}

// ---------------------------------------------------------------------------
// Reduce: out = state + sum_y partials. grid (128, 2) x 256 threads.
// ---------------------------------------------------------------------------
__global__ __launch_bounds__(256) void reduce_kernel(const unsigned short* __restrict__ part,
                                                     const float* __restrict__ S,
                                                     float* __restrict__ out, int nY) {
    const int t = threadIdx.x;
    const int jx = blockIdx.x;  // 0..127
    const int s = blockIdx.y;   // 0..1
    const int w = t >> 6, lane = t & 63, q = lane >> 4, ln = lane & 15;

    float acc[2][2][4];
#pragma unroll
    for (int jj = 0; jj < 2; ++jj)
#pragma unroll
        for (int c = 0; c < 2; ++c)
#pragma unroll
            for (int r = 0; r < 4; ++r) acc[jj][c][r] = 0.f;

    for (int y = 0; y < nY; ++y) {
        const unsigned short* pb = part + (size_t)(y * 128 + jx) * 8192;
#pragma unroll
        for (int jj = 0; jj < 2; ++jj) {
            const int jm = s * 2 + jj;
            const uint4 v = *(const uint4*)(pb + jm * 2048 + t * 8);
            acc[jj][0][0] += f16lo(v.x); acc[jj][0][1] += f16hi(v.x);
            acc[jj][0][2] += f16lo(v.y); acc[jj][0][3] += f16hi(v.y);
            acc[jj][1][0] += f16lo(v.z); acc[jj][1][1] += f16hi(v.z);
            acc[jj][1][2] += f16lo(v.w); acc[jj][1][3] += f16hi(v.w);
        }
    }
#pragma unroll
    for (int jj = 0; jj < 2; ++jj)
#pragma unroll
        for (int c = 0; c < 2; ++c) {
            const int g = w * 2 + c;
            const int bb = g >> 2, dt = g & 3;
            const int j = jx * 64 + (s * 2 + jj) * 16 + q * 4;
#pragma unroll
            for (int r = 0; r < 4; ++r) {
                const int idx = (bb * NN + j + r) * DD + dt * 16 + ln;
                out[idx] = S[idx] + acc[jj][c][r];
            }
        }
}

// ---------------------------------------------------------------------------
extern "C" void kernel_launch(void* const* d_in, const int* in_sizes, int n_in,
                              void* d_out, int out_size, void* d_ws, size_t ws_size,
                              hipStream_t stream) {
    const float* states = (const float*)d_in[0];  // [B,N,D]
    const float* prof   = (const float*)d_in[1];  // [B,N]
    const float* emb    = (const float*)d_in[2];  // [N,E]
    const float* W      = (const float*)d_in[3];  // [1,E,E]
    const float* bias   = (const float*)d_in[4];  // [1]
    float* out = (float*)d_out;

    short* P_bf = (short*)d_ws;                 // 1 MB
    short* U_bf = P_bf + NN * EE;               // 1 MB
    short* es_t = U_bf + NN * EE;               // 2 MB
    unsigned short* part = (unsigned short*)(es_t + (size_t)NB * 64 * NN);

    // partials = nY * 2 MB; nY=16 (2048 blocks -> 8 blocks/CU available)
    const size_t need16 = (size_t)(4 + 32) * 1024 * 1024;
    const int nY = (ws_size >= need16) ? 16 : 8;

    p_kernel<<<NN / 4, 256, 0, stream>>>(emb, W, P_bf, U_bf);
    es_kernel<<<NB * NN / 32, 256, 0, stream>>>(states, prof, es_t);
    transfer_kernel<<<dim3(128, nY), 256, 0, stream>>>(P_bf, U_bf, es_t, bias, part);
    reduce_kernel<<<dim3(128, 2), 256, 0, stream>>>(part, states, out, nY);
}